// Round 10
// baseline (1145.865 us; speedup 1.0000x reference)
//
#include <hip/hip_runtime.h>
#include <cstdint>
#include <cstddef>

// Problem constants (fixed by the reference)
#define B_ROWS 8192
#define E_EXP  8

typedef unsigned short ushort_t;
typedef short bf16x8 __attribute__((ext_vector_type(8)));
typedef float f32x4  __attribute__((ext_vector_type(4)));

__device__ __forceinline__ ushort_t f2b(float f) {
  union { float f; unsigned int i; } v; v.f = f;
  unsigned int u = v.i;
  unsigned int r = (u + 0x7fffu + ((u >> 16) & 1u)) >> 16;
  return (ushort_t)r;
}
__device__ __forceinline__ float eluf(float x) {
  return x > 0.f ? x : (__expf(x) - 1.f);
}

// ---------------------------------------------------------------------------
// Weight transpose + fp32->bf16: w flat [R][C] -> wT [C][R] bf16.
// ---------------------------------------------------------------------------
__global__ void transpose_k(const float* __restrict__ src,
                            ushort_t* __restrict__ dst, int R, int C) {
  __shared__ ushort_t tile[64][65];
  int c0 = blockIdx.x * 64, r0 = blockIdx.y * 64;
  int x = threadIdx.x, y = threadIdx.y;
#pragma unroll
  for (int i = 0; i < 4; ++i)
    tile[y + 16 * i][x] = f2b(src[(size_t)(r0 + y + 16 * i) * C + c0 + x]);
  __syncthreads();
#pragma unroll
  for (int i = 0; i < 4; ++i)
    dst[(size_t)(c0 + y + 16 * i) * R + r0 + x] = tile[x][y + 16 * i];
}

// ---------------------------------------------------------------------------
// Gating MLP (pure fp32), float4-unrolled j-loops. Emits:
//   coeff[b][e]  softmax probs
//   rat2[b][e]   2-way split {0-3},{4-7}: e in {3,7}: c_e; else c_e/c_{e+1}
//   rat4[b][e]   4-way split {0,1}..{6,7}: e odd: c_e; e even: c_e/c_{e+1}
// ---------------------------------------------------------------------------
__global__ __launch_bounds__(128) void gate_k(
    const float* __restrict__ z, const float* __restrict__ c,
    const float* __restrict__ g0w, const float* __restrict__ g0b,
    const float* __restrict__ g1w, const float* __restrict__ g1b,
    const float* __restrict__ g2w, const float* __restrict__ g2b,
    float* __restrict__ coeff, float* __restrict__ rat2,
    float* __restrict__ rat4) {
  __shared__ float xs[4][320];
  __shared__ float h1[4][128];
  __shared__ float h2[4][128];
  __shared__ float lg[4][8];
  __shared__ float pr[4][8];
  int t = threadIdx.x;
  int r0 = blockIdx.x * 4;
  for (int idx = t; idx < 4 * 320; idx += 128) {
    int r = idx / 320, j = idx % 320;
    xs[r][j] = (j < 64) ? z[(size_t)(r0 + r) * 64 + j]
                        : c[(size_t)(r0 + r) * 256 + j - 64];
  }
  __syncthreads();
  {
    float bb = g0b[t];
    float a0 = bb, a1 = bb, a2 = bb, a3 = bb;
    for (int j = 0; j < 320; j += 4) {
      float w0 = g0w[j * 128 + t];
      float w1 = g0w[(j + 1) * 128 + t];
      float w2 = g0w[(j + 2) * 128 + t];
      float w3 = g0w[(j + 3) * 128 + t];
      float4 x0 = *(const float4*)&xs[0][j];
      float4 x1 = *(const float4*)&xs[1][j];
      float4 x2 = *(const float4*)&xs[2][j];
      float4 x3 = *(const float4*)&xs[3][j];
      a0 += x0.x * w0 + x0.y * w1 + x0.z * w2 + x0.w * w3;
      a1 += x1.x * w0 + x1.y * w1 + x1.z * w2 + x1.w * w3;
      a2 += x2.x * w0 + x2.y * w1 + x2.z * w2 + x2.w * w3;
      a3 += x3.x * w0 + x3.y * w1 + x3.z * w2 + x3.w * w3;
    }
    h1[0][t] = eluf(a0); h1[1][t] = eluf(a1);
    h1[2][t] = eluf(a2); h1[3][t] = eluf(a3);
  }
  __syncthreads();
  {
    float bb = g1b[t];
    float a0 = bb, a1 = bb, a2 = bb, a3 = bb;
    for (int j = 0; j < 128; j += 4) {
      float w0 = g1w[j * 128 + t];
      float w1 = g1w[(j + 1) * 128 + t];
      float w2 = g1w[(j + 2) * 128 + t];
      float w3 = g1w[(j + 3) * 128 + t];
      float4 x0 = *(const float4*)&h1[0][j];
      float4 x1 = *(const float4*)&h1[1][j];
      float4 x2 = *(const float4*)&h1[2][j];
      float4 x3 = *(const float4*)&h1[3][j];
      a0 += x0.x * w0 + x0.y * w1 + x0.z * w2 + x0.w * w3;
      a1 += x1.x * w0 + x1.y * w1 + x1.z * w2 + x1.w * w3;
      a2 += x2.x * w0 + x2.y * w1 + x2.z * w2 + x2.w * w3;
      a3 += x3.x * w0 + x3.y * w1 + x3.z * w2 + x3.w * w3;
    }
    h2[0][t] = eluf(a0); h2[1][t] = eluf(a1);
    h2[2][t] = eluf(a2); h2[3][t] = eluf(a3);
  }
  __syncthreads();
  if (t < 32) {
    int r = t >> 3, e = t & 7;
    float a = g2b[e];
    for (int j = 0; j < 128; ++j) a += h2[r][j] * g2w[j * 8 + e];
    lg[r][e] = a;
  }
  __syncthreads();
  if (t < 32) {
    int r = t >> 3, e = t & 7;
    float mx = lg[r][0];
#pragma unroll
    for (int i = 1; i < 8; ++i) mx = fmaxf(mx, lg[r][i]);
    float s = 0.f;
#pragma unroll
    for (int i = 0; i < 8; ++i) s += __expf(lg[r][i] - mx);
    float p = __expf(lg[r][e] - mx) / s;
    coeff[(size_t)(r0 + r) * 8 + e] = p;
    pr[r][e] = p;
  }
  __syncthreads();
  if (t < 32) {
    int r = t >> 3, e = t & 7;
    float pe = pr[r][e];
    float ratio = (e < 7) ? pe / fmaxf(pr[r][e + 1], 1e-30f) : pe;
    rat2[(size_t)(r0 + r) * 8 + e] = (e == 3 || e == 7) ? pe : ratio;
    rat4[(size_t)(r0 + r) * 8 + e] = (e & 1) ? pe : ratio;
  }
}

// ---------------------------------------------------------------------------
// LayerNorm over concat([z_row, prev_row]) -> out [B][J] bf16.
//   p1 != null : prev = elu(p0 + p1 + sum_e cf[row,e]*bias[e,:])
//   p1 == null : prev = p0 raw (layer-0 path reading c)
// ---------------------------------------------------------------------------
__global__ __launch_bounds__(128) void ln_concat_k(
    const float* __restrict__ z, const float* __restrict__ p0,
    const float* __restrict__ p1, const float* __restrict__ cf,
    const float* __restrict__ bias, ushort_t* __restrict__ out,
    int Pw, int J) {
  int row = blockIdx.x, t = threadIdx.x;
  float vals[9];
  int n = (J + 127) >> 7;
  float cr[8];
  if (p1) {
#pragma unroll
    for (int e = 0; e < 8; ++e) cr[e] = cf[(size_t)row * 8 + e];
  }
  float s = 0.f, s2 = 0.f;
  for (int k = 0; k < n; ++k) {
    int i = t + (k << 7);
    float x = 0.f;
    if (i < J) {
      if (i < 64) {
        x = z[(size_t)row * 64 + i];
      } else if (p1) {
        int j = i - 64;
        float v = p0[(size_t)row * Pw + j] + p1[(size_t)row * Pw + j];
#pragma unroll
        for (int e = 0; e < 8; ++e) v += cr[e] * bias[(size_t)e * Pw + j];
        x = eluf(v);
      } else {
        x = p0[(size_t)row * Pw + i - 64];
      }
    }
    vals[k] = x; s += x; s2 += x * x;
  }
  for (int off = 32; off > 0; off >>= 1) {
    s += __shfl_down(s, off);
    s2 += __shfl_down(s2, off);
  }
  __shared__ float red[4];
  int wid = t >> 6, lane = t & 63;
  if (lane == 0) { red[wid * 2] = s; red[wid * 2 + 1] = s2; }
  __syncthreads();
  float S = red[0] + red[2], S2 = red[1] + red[3];
  float inv = 1.f / (float)J;
  float m = S * inv;
  float var = S2 * inv - m * m;
  float rstd = rsqrtf(var + 1e-5f);
  for (int k = 0; k < n; ++k) {
    int i = t + (k << 7);
    if (i < J) out[(size_t)row * J + i] = f2b((vals[k] - m) * rstd);
  }
}

// ---------------------------------------------------------------------------
// Fused MoE GEMM, round 16: W STREAMED GLOBAL->REGISTER (off the LDS pipe),
// A via gload_lds + counted vmcnt. 256x256 tile, 8 waves 2M x 4N.
//
// Round-8 post-mortem: 4 waves/SIMD neutral, but LDS traffic +33% at equal
// time -> the LDS pipe is the contested resource (A reads + W reads + both
// stage streams; floor ~3600 cyc vs measured 5590/K-tile). W frags have only
// 2-way cross-wave reuse — not worth the LDS round-trip (32KB wr + 64KB rd
// per K-tile). This round streams W directly to registers per wave
// (global_load_dwordx4, L2-resident: shared by 4 co-XCD bt-blocks), one
// K-tile ahead, in a NAMED register double-buffer (wfA/wfB, 2-tile-unrolled
// loop — rule #20: no runtime-indexed frag arrays). LDS now carries A only:
// ~1800 cyc floor; vmem carries W: ~1170 cyc at L2 rate (separate pipe,
// prefetched a full tile ahead). MFMA 2484. Worst case serial LDS+MFMA:
// ~4300 vs 5590 cyc.
//
// vmcnt discipline per K-tile: issue 4 A-stages (next tile) then 8 W-loads
// (next tile); at tile end `vmcnt(8)` drains exactly the 4 A-stages (oldest)
// and leaves the W-loads in flight — the compiler inserts its own counted
// wait for the W registers at their first use next tile. One barrier per
// K-tile (no LDS W-reads to protect; A buf alternates).
//
// LDS: A 2buf x 2ks x 16KB = 64KB + scales 9KB = 73KB. Grid 256 = 1/CU via
// expert split: layers 0-2 ez=2 (rat2, partials combined in ln_concat_k),
// layer 3 ez=4 (rat4, combine4_k). W offsets linear across experts; A col
// resets per expert. XCD = bt%8 (A-panel L2-resident per XCD).
// ---------------------------------------------------------------------------
__device__ __forceinline__ void gload16(const void* g, void* l) {
  __builtin_amdgcn_global_load_lds(
      (const __attribute__((address_space(1))) void*)g,
      (__attribute__((address_space(3))) void*)l, 16, 0, 0);
}

__global__ __launch_bounds__(512, 2) void moe_gemm_k(
    const ushort_t* __restrict__ inp,   // [B][J] bf16 (LN'd concat)
    const ushort_t* __restrict__ wT,    // [K][E*J] bf16 (pre-transposed)
    const float* __restrict__ scales,   // [B][8] Horner boundary scales
    float* __restrict__ outp,           // [nez][B][K] fp32 partials
    int J, int K, int ne) {
  const int Kd = E_EXP * J;
  const int nj = J >> 6;        // BK=64 tiles per expert
  const int nt = ne * nj;       // total K-tiles (even for all layers)
  __shared__ short As[2][2][16 * 512];   // [buf][ks][blk*512 + l*8]  64KB
  __shared__ float scale_s[256 * 9];     // [row][e] stride 9 (bank pad)

  const int t = threadIdx.x;
  const int w = t >> 6, l = t & 63;
  const int wm = w >> 2, wn = w & 3;     // 2M x 4N wave layout, 128x64/wave
  const int bt = blockIdx.x, ct = blockIdx.y, ez = blockIdx.z;
  const int e0 = ez * ne;
  outp += (size_t)ez * (size_t)B_ROWS * (size_t)K;

#pragma unroll
  for (int i = 0; i < 4; ++i) {
    int idx = t + (i << 9);  // 0..2047
    int rw = idx >> 3, e = idx & 7;
    scale_s[rw * 9 + e] = scales[(size_t)(bt * 256 + rw) * 8 + e];
  }

  // A stage bases: wave w owns blocks w*2, w*2+1 of each 16-block ks-half.
  size_t abase[2];
#pragma unroll
  for (int i = 0; i < 2; ++i)
    abase[i] = (size_t)(bt * 256 + (w * 2 + i) * 16 + (l & 15)) * J +
               ((l >> 4) * 8);
  // W frag row bases (global, per lane): frag fn covers cols wn*64+fn*16.
  size_t wrow[4];
#pragma unroll
  for (int fn = 0; fn < 4; ++fn)
    wrow[fn] = (size_t)(ct * 256 + wn * 64 + fn * 16 + (l & 15)) * Kd +
               (size_t)e0 * J + ((l >> 4) * 8);

  int s_acol = 0, s_wcol = 0, sjt = 0;  // stage-side counters (next tile)

  auto stageA4 = [&](int nb) {
#pragma unroll
    for (int ks = 0; ks < 2; ++ks)
#pragma unroll
      for (int i = 0; i < 2; ++i)
        gload16(inp + abase[i] + s_acol + ks * 32,
                &As[nb][ks][(w * 2 + i) * 512]);
  };
  auto advance = [&]() {
    s_wcol += 64;
    if (++sjt == nj) { sjt = 0; s_acol = 0; } else { s_acol += 64; }
  };

#define LOADW(dst)                                                         \
  _Pragma("unroll") for (int ks = 0; ks < 2; ++ks)                         \
      _Pragma("unroll") for (int fn = 0; fn < 4; ++fn) dst[ks][fn] =       \
          *(const bf16x8*)(wT + wrow[fn] + s_wcol + ks * 32);

#define RD_A(dst, b_, ks_, MB)                                             \
  _Pragma("unroll") for (int q = 0; q < 4; ++q) dst[q] =                   \
      *(const bf16x8*)(&As[b_][ks_][(wm * 8 + (MB) + q) * 512 + l * 8]);

#define MM16(MB, AF, BF)                                                   \
  __builtin_amdgcn_s_setprio(1);                                           \
  _Pragma("unroll") for (int q = 0; q < 4; ++q)                            \
      _Pragma("unroll") for (int fn = 0; fn < 4; ++fn) acc[(MB) + q][fn] = \
          __builtin_amdgcn_mfma_f32_16x16x32_bf16(AF[q], BF[fn],           \
                                                  acc[(MB) + q][fn], 0, 0, 0); \
  __builtin_amdgcn_s_setprio(0);

#define COMPUTE(b_, WF)                                                    \
  {                                                                        \
    bf16x8 af[4];                                                          \
    RD_A(af, b_, 0, 0); MM16(0, af, WF[0]);                                \
    RD_A(af, b_, 0, 4); MM16(4, af, WF[0]);                                \
    RD_A(af, b_, 1, 0); MM16(0, af, WF[1]);                                \
    RD_A(af, b_, 1, 4); MM16(4, af, WF[1]);                                \
  }

  f32x4 acc[8][4];
#pragma unroll
  for (int fm = 0; fm < 8; ++fm)
#pragma unroll
    for (int fn = 0; fn < 4; ++fn) acc[fm][fn] = (f32x4){0.f, 0.f, 0.f, 0.f};

  bf16x8 wfA[2][4], wfB[2][4];

  int cjt = 0, cle = 0;  // compute-side counters
  auto boundary = [&]() {
    if (++cjt == nj) {
      cjt = 0;
      int e = e0 + cle;
      ++cle;
#pragma unroll
      for (int fi = 0; fi < 8; ++fi) {
        int rbase = wm * 128 + fi * 16 + ((l >> 4) << 2);
#pragma unroll
        for (int rr = 0; rr < 4; ++rr) {
          float rv = scale_s[(rbase + rr) * 9 + e];
#pragma unroll
          for (int fn = 0; fn < 4; ++fn) acc[fi][fn][rr] *= rv;
        }
      }
    }
  };

  // prologue: tile 0 -> A buf0 + wfA; full drain once (publishes scale_s too)
  stageA4(0);
  LOADW(wfA);
  advance();
  __syncthreads();

  for (int tp = 0; tp < nt; tp += 2) {
    const bool m2 = (tp + 2 < nt);
    // ---- even tile tp: A buf0 + wfA; prefetch tile tp+1 (buf1 + wfB)
    stageA4(1);
    LOADW(wfB);
    advance();
    COMPUTE(0, wfA);
    boundary();
    asm volatile("s_waitcnt vmcnt(8)" ::: "memory");  // A-stages (oldest 4)
    asm volatile("s_barrier" ::: "memory");
    // ---- odd tile tp+1: A buf1 + wfB; prefetch tile tp+2 (buf0 + wfA)
    if (m2) {
      stageA4(0);
      LOADW(wfA);
      advance();
    }
    COMPUTE(1, wfB);
    boundary();
    if (m2) asm volatile("s_waitcnt vmcnt(8)" ::: "memory");
    else    asm volatile("s_waitcnt vmcnt(0)" ::: "memory");
    asm volatile("s_barrier" ::: "memory");
  }

  // epilogue: raw fp32 partial store (bias/ELU fused downstream)
#pragma unroll
  for (int fi = 0; fi < 8; ++fi) {
#pragma unroll
    for (int rr = 0; rr < 4; ++rr) {
      int row = wm * 128 + fi * 16 + ((l >> 4) << 2) + rr;
      size_t orow = (size_t)(bt * 256 + row) * K + ct * 256;
#pragma unroll
      for (int fn = 0; fn < 4; ++fn) {
        int col = wn * 64 + fn * 16 + (l & 15);
        outp[orow + col] = acc[fi][fn][rr];
      }
    }
  }
}

// ---------------------------------------------------------------------------
// Final combine for layer 3 (4-way expert split, K=512, no activation):
//   out = p0+p1+p2+p3 + coeff@bias
// ---------------------------------------------------------------------------
__global__ __launch_bounds__(256) void combine4_k(
    const float* __restrict__ pb, const float* __restrict__ cf,
    const float* __restrict__ bias, float* __restrict__ out, int K) {
  size_t i4 = (size_t)blockIdx.x * 256 + threadIdx.x;
  size_t total = (size_t)B_ROWS * (size_t)K;
  size_t base = i4 * 4;
  if (base >= total) return;
  int row = (int)(base / (size_t)K);
  int col = (int)(base % (size_t)K);
  size_t s4 = total >> 2;  // partial stride in f32x4 units
  const f32x4* p4 = (const f32x4*)pb;
  f32x4 v = p4[i4] + p4[i4 + s4] + p4[i4 + 2 * s4] + p4[i4 + 3 * s4];
#pragma unroll
  for (int e = 0; e < 8; ++e) {
    float ce = cf[(size_t)row * 8 + e];
    f32x4 bv = *(const f32x4*)(bias + (size_t)e * K + col);
    v += ce * bv;
  }
  ((f32x4*)out)[i4] = v;
}

// ---------------------------------------------------------------------------
extern "C" void kernel_launch(void* const* d_in, const int* in_sizes, int n_in,
                              void* d_out, int out_size, void* d_ws, size_t ws_size,
                              hipStream_t stream) {
  const float* z   = (const float*)d_in[0];
  const float* c   = (const float*)d_in[1];
  const float* g0w = (const float*)d_in[2];
  const float* g0b = (const float*)d_in[3];
  const float* g1w = (const float*)d_in[4];
  const float* g1b = (const float*)d_in[5];
  const float* g2w = (const float*)d_in[6];
  const float* g2b = (const float*)d_in[7];
  const float* w0  = (const float*)d_in[8];
  const float* b0  = (const float*)d_in[9];
  const float* w1  = (const float*)d_in[10];
  const float* b1  = (const float*)d_in[11];
  const float* w2  = (const float*)d_in[12];
  const float* b2  = (const float*)d_in[13];
  const float* w3  = (const float*)d_in[14];
  const float* b3  = (const float*)d_in[15];

  char* ws = (char*)d_ws;
  size_t o = 0;
  auto alloc = [&](size_t bytes) {
    void* p = ws + o;
    o += (bytes + 255) & ~(size_t)255;
    return p;
  };
  ushort_t* wT0 = (ushort_t*)alloc((size_t)2560 * 1024 * 2);
  ushort_t* wT1 = (ushort_t*)alloc((size_t)8704 * 1024 * 2);
  ushort_t* wT2 = (ushort_t*)alloc((size_t)8704 * 1024 * 2);
  ushort_t* wT3 = (ushort_t*)alloc((size_t)8704 * 512 * 2);
  float*    cf   = (float*)alloc((size_t)B_ROWS * 8 * 4);
  float*    rat2 = (float*)alloc((size_t)B_ROWS * 8 * 4);
  float*    rat4 = (float*)alloc((size_t)B_ROWS * 8 * 4);
  ushort_t* inp  = (ushort_t*)alloc((size_t)B_ROWS * 1088 * 2);
  float*    pb   = (float*)alloc((size_t)2 * B_ROWS * 1024 * 4);  // partials

  dim3 tb(64, 16);
  transpose_k<<<dim3(1024 / 64, 2560 / 64), tb, 0, stream>>>(w0, wT0, 2560, 1024);
  transpose_k<<<dim3(1024 / 64, 8704 / 64), tb, 0, stream>>>(w1, wT1, 8704, 1024);
  transpose_k<<<dim3(1024 / 64, 8704 / 64), tb, 0, stream>>>(w2, wT2, 8704, 1024);
  transpose_k<<<dim3(512 / 64, 8704 / 64), tb, 0, stream>>>(w3, wT3, 8704, 512);

  gate_k<<<B_ROWS / 4, 128, 0, stream>>>(z, c, g0w, g0b, g1w, g1b, g2w, g2b,
                                         cf, rat2, rat4);

  float* p1v = pb + (size_t)B_ROWS * 1024;

  // layer 0: J=320, K=1024, 2-way expert split (ne=4), grid 32x4x2 = 256
  ln_concat_k<<<B_ROWS, 128, 0, stream>>>(z, c, nullptr, nullptr, nullptr,
                                          inp, 256, 320);
  moe_gemm_k<<<dim3(32, 4, 2), 512, 0, stream>>>(inp, wT0, rat2, pb, 320, 1024, 4);
  // layer 1: J=1088, K=1024 (ln fuses partial combine + b0-mix + elu)
  ln_concat_k<<<B_ROWS, 128, 0, stream>>>(z, pb, p1v, cf, b0, inp, 1024, 1088);
  moe_gemm_k<<<dim3(32, 4, 2), 512, 0, stream>>>(inp, wT1, rat2, pb, 1088, 1024, 4);
  // layer 2
  ln_concat_k<<<B_ROWS, 128, 0, stream>>>(z, pb, p1v, cf, b1, inp, 1024, 1088);
  moe_gemm_k<<<dim3(32, 4, 2), 512, 0, stream>>>(inp, wT2, rat2, pb, 1088, 1024, 4);
  // layer 3: J=1088, K=512, 4-way expert split (ne=2), grid 32x2x4 = 256
  ln_concat_k<<<B_ROWS, 128, 0, stream>>>(z, pb, p1v, cf, b2, inp, 1024, 1088);
  moe_gemm_k<<<dim3(32, 2, 4), 512, 0, stream>>>(inp, wT3, rat4, pb, 1088, 512, 2);
  combine4_k<<<(B_ROWS * 512) / 1024, 256, 0, stream>>>(pb, cf, b3,
                                                        (float*)d_out, 512);
}